// Round 17
// baseline (264.321 us; speedup 1.0000x reference)
//
#include <hip/hip_runtime.h>

// LaneATT head, MI355X.
// all_feat af[b][1024][1536] bf16: cols 0:768 = att_feat (GEMM2 C), 768:1536 = baf (gather).
// wcat is 128x1536 matching af col geometry (k 704..767 and 1472..1535 zero).
// Pipeline (6 dispatches): k_prep(prep+biaspad+conv, 512thr) -> k_gat(gather+transpose)
//  -> G1=k_g8(af_hi x attn_wb^T + attn_b -> att) -> softmax(wave-per-row)
//  -> G2=k_g8(att x bafT^T -> af_lo) -> G3=k_g3 (fused epilogue).
// k_g8 (measured-best): BM=256 BN=128 BK=32, 3-slot LDS ring (72KB -> 2 blocks/CU,
//  4 waves/SIMD), 1 barrier + counted vmcnt(3) per K-tile (never 0 in steady state).
// Geometry A/B/C log: r12 BN=128/2blk = 57.4us ; r13 global-B = 125us ; r15 BN=256/1blk
//  = 66us. 4 waves/SIMD TLP wins; do not revisit.
// r17 fix: conv weights via wave-uniform GLOBAL reads (scalar s_load path) — the old
//  LDS-broadcast version issued 8 ds_read per FMA (~55us hidden at profile rank #6).
// ws layout: wcat @0 (393,216) | attn_wb @393,216 (1,441,792) | af @1,835,008 (100,663,296)
//  | bafT @102,498,304 (50,331,648) | att @152,829,952 (67,108,864; feat f32 + xn live
//  pre-G1) | attn_bp @219,938,816 (4,096). End 219,942,912.

typedef unsigned short u16;
typedef short short8 __attribute__((ext_vector_type(8)));
typedef float f32x4 __attribute__((ext_vector_type(4)));

__device__ __forceinline__ u16 f2bf(float f) {
    union { float f; unsigned u; } v; v.f = f;
    unsigned r = v.u + 0x7FFFu + ((v.u >> 16) & 1u);
    return (u16)(r >> 16);
}
__device__ __forceinline__ float bf2f(u16 u) {
    union { unsigned u; float f; } v; v.u = ((unsigned)u) << 16;
    return v.f;
}

__device__ __forceinline__ void gload16(const u16* gsrc, u16* ldst) {
    __builtin_amdgcn_global_load_lds(
        (const __attribute__((address_space(1))) unsigned int*)gsrc,
        (__attribute__((address_space(3))) unsigned int*)ldst, 16, 0, 0);
}

#define DSR(d, a, off) asm volatile("ds_read_b128 %0, %1 offset:" #off : "=v"(d) : "v"(a))
#define LGKMN(n) do { asm volatile("s_waitcnt lgkmcnt(" #n ")" ::: "memory"); \
                      __builtin_amdgcn_sched_barrier(0); } while (0)
#define WVM(n) do { asm volatile("s_waitcnt vmcnt(" #n ")" ::: "memory"); \
                    __builtin_amdgcn_sched_barrier(0); } while (0)
#define BAR do { __builtin_amdgcn_s_barrier(); \
                 __builtin_amdgcn_sched_barrier(0); } while (0)

// ---------- fused prep + conv (512 threads):
// [0,1408) attnw | [1408,1792) wcat | [1792,1814) xn | 1814 biaspad | [1815,2071) conv
__global__ __launch_bounds__(512) void k_prep(const float* __restrict__ attn_w,
                                              const float* __restrict__ cls_w,
                                              const float* __restrict__ reg_w,
                                              const int* __restrict__ cut_xs,
                                              const void* __restrict__ mask,
                                              const float* __restrict__ attn_b,
                                              const float* __restrict__ x,
                                              const float* __restrict__ w1,
                                              const float* __restrict__ b1,
                                              u16* __restrict__ attn_wb,
                                              u16* __restrict__ wcat,
                                              int* __restrict__ xn,
                                              float* __restrict__ attn_bp,
                                              float* __restrict__ feat) {
    const int blk = blockIdx.x, tid = threadIdx.x;
    if (blk < 1408) {
        int i = blk * 512 + tid;                    // 1024*704 = 720896 exactly
        int r = i / 704;
        attn_wb[i] = (r < 999) ? f2bf(attn_w[i]) : (u16)0;
        return;
    }
    if (blk < 1792) {
        int i = (blk - 1408) * 512 + tid;           // 128*1536 = 196608 exactly
        int o = i / 1536, k = i - o * 1536;
        int ksrc = -1;
        if (k < 704) ksrc = k;
        else if (k >= 768 && k < 1472) ksrc = k - 64;
        float v = 0.f;
        if (ksrc >= 0) {
            if (o < 2) v = cls_w[o * 1408 + ksrc];
            else if (o < 75) v = reg_w[(o - 2) * 1408 + ksrc];
        }
        wcat[i] = f2bf(v);
        return;
    }
    if (blk < 1814) {
        const unsigned char* m8 = (const unsigned char*)mask;
        int any = 0;
        for (int i = tid; i < 11000; i += 512)
            if ((i & 3) && m8[i]) any = 1;
        any = __any(any) ? 1 : 0;
        __shared__ int sh[8];
        if ((tid & 63) == 0) sh[tid >> 6] = any;
        __syncthreads();
        int isb8 = 0;
        #pragma unroll
        for (int q = 0; q < 8; ++q) isb8 |= sh[q];
        int i = (blk - 1792) * 512 + tid;
        if (i < 11000) {
            int inv = isb8 ? (int)m8[i] : ((const int*)mask)[i];
            int n = i / 11, y = i - n * 11;
            xn[i] = inv ? -1 : cut_xs[n * 704 + y];
        }
        return;
    }
    if (blk == 1814) {
        for (int c = tid; c < 1024; c += 512)
            attn_bp[c] = (c < 999) ? attn_b[c] : 0.f;
        return;
    }
    // conv 1x1: idx -> (b, og); thread = (pixel p, K-half kh).
    // Weights are wave-uniform -> global reads lower to scalar s_load (K$),
    // keeping the vector pipe free: per c-iter = 1 coalesced x load + 8 FMA.
    {
        __shared__ float part[8][224];
        const int idx = blk - 1815;
        const int b = idx & 31, og = idx >> 5;
        const int p = tid & 255, kh = tid >> 8;
        float acc[8] = {};
        if (p < 220) {
            const float* xb = x + (size_t)b * 512 * 220 + kh * 256 * 220 + p;
            const float* wb = w1 + (size_t)(og * 8) * 512 + kh * 256;  // uniform
            #pragma unroll 8
            for (int c = 0; c < 256; ++c) {
                float xv = xb[(size_t)c * 220];
                #pragma unroll
                for (int o = 0; o < 8; ++o)
                    acc[o] = fmaf(xv, wb[o * 512 + c], acc[o]);
            }
        }
        if (kh == 1 && p < 220) {
            #pragma unroll
            for (int o = 0; o < 8; ++o) part[o][p] = acc[o];
        }
        __syncthreads();
        if (kh == 0 && p < 220) {
            float* fo = feat + (size_t)b * 14080 + (og * 8) * 220 + p;
            #pragma unroll
            for (int o = 0; o < 8; ++o)
                fo[(size_t)o * 220] = acc[o] + part[o][p] + b1[og * 8 + o];
        }
    }
}

// ---------- fused gather + transpose ----------
__global__ __launch_bounds__(256) void k_gat(const float* __restrict__ feat,
                                             const int* __restrict__ xn,
                                             u16* __restrict__ af,
                                             u16* __restrict__ bafT) {
    __shared__ __attribute__((aligned(16))) u16 tl[64 * 64];
    const int mt = blockIdx.x & 15, dt = blockIdx.x >> 4;
    const int b = blockIdx.y;
    const int tid = threadIdx.x;
    const float* fb = feat + (size_t)b * 14080;
    #pragma unroll
    for (int h = 0; h < 2; ++h) {
        const int nl = (tid >> 3) + h * 32;
        const int n = mt * 64 + nl;
        const int dc = (tid & 7) * 8;
        const int d8 = dt * 64 + dc;
        short8 o = {0, 0, 0, 0, 0, 0, 0, 0};
        #pragma unroll
        for (int j = 0; j < 8; ++j) {
            int d = d8 + j;
            float v = 0.f;
            if (n < 1000 && d < 704) {
                int c = d / 11, y = d - c * 11;
                int xv = xn[n * 11 + y];
                if (xv >= 0) v = fb[c * 220 + y * 20 + xv];
            }
            o[j] = (short)f2bf(v);
        }
        *(short8*)&af[((size_t)(b * 1024 + n)) * 1536 + 768 + d8] = o;
        int key = ((nl >> 3) + nl) & 7;
        *(short8*)&tl[nl * 64 + (((tid & 7) ^ key) * 8)] = o;
    }
    __syncthreads();
    u16* dst = bafT + ((size_t)b * 768 + dt * 64) * 1024 + mt * 64;
    #pragma unroll
    for (int h = 0; h < 2; ++h) {
        int slot = h * 256 + tid;
        int dl = slot >> 3, m8 = (slot & 7) * 8;
        short8 v;
        #pragma unroll
        for (int j = 0; j < 8; ++j) {
            int m = m8 + j;
            int key = ((m >> 3) + m) & 7;
            v[j] = (short)tl[m * 64 + (((dl >> 3) ^ key) * 8) + (dl & 7)];
        }
        *(short8*)&dst[(size_t)dl * 1024 + m8] = v;
    }
}

// ---------- GEMM engine (measured-best): BM=256 BN=128 BK=32, ring-3 ----------
__global__ __launch_bounds__(512, 4) void k_g8(const u16* __restrict__ A, long sAb, int lda,
                                               const u16* __restrict__ Bt, long sBb, int ldb,
                                               void* __restrict__ Cv, long sCb, int ldc,
                                               int ntN, int tpb, int nwg, int ks, int cf32,
                                               const float* __restrict__ bias) {
    __shared__ __attribute__((aligned(16))) u16 LDS[36864];   // 72 KB
    const int bid = blockIdx.x;
    const int cpx = nwg >> 3;                         // bijective XCD swizzle (nwg%8==0)
    const int logical = (bid & 7) * cpx + (bid >> 3);
    const int batch = logical / tpb;
    const int t0 = logical - batch * tpb;
    const int tM = t0 / ntN, tN = t0 - tM * ntN;
    A  += (size_t)batch * sAb;
    Bt += (size_t)batch * sBb;

    const int tid = threadIdx.x;
    const int lane = tid & 63, w = tid >> 6;
    const int wr = w >> 1, wc = w & 1;                // wave tile: rows wr*64, cols wc*64
    const int l15 = lane & 15;
    const int lkswz = ((lane >> 4) ^ ((l15 >> 1) & 3)) * 8;
    const u16* Abase = A + (size_t)tM * 256 * lda;
    const u16* Bbase = Bt + (size_t)tN * 128 * ldb;
    const int srow = tid >> 2;
    const int sgc = (((tid & 3) ^ ((tid >> 3) & 3)) * 8);

    f32x4 acc[4][4] = {};

    auto SG = [&](int t) {
        const int s = (t % 3) * 12288;                // slot base (u16)
        const u16* ga = Abase + (size_t)srow * lda + t * 32 + sgc;
        gload16(ga, &LDS[s + tid * 8]);
        gload16(ga + (size_t)128 * lda, &LDS[s + 4096 + tid * 8]);
        gload16(Bbase + (size_t)srow * ldb + t * 32 + sgc, &LDS[s + 8192 + tid * 8]);
    };

    SG(0);
    if (ks > 1) { SG(1); WVM(3); } else { WVM(0); }
    BAR;

    const unsigned aAl = (unsigned)(size_t)&LDS[(wr * 64 + l15) * 32 + lkswz];
    const unsigned aBl = (unsigned)(size_t)&LDS[8192 + (wc * 64 + l15) * 32 + lkswz];

    for (int t = 0; t < ks; ++t) {
        const unsigned sb = (unsigned)(t % 3) * 24576u;
        short8 av[4], bv[4];
        {
            unsigned aA = aAl + sb, aB = aBl + sb;
            DSR(bv[0], aB, 0); DSR(bv[1], aB, 1024); DSR(bv[2], aB, 2048); DSR(bv[3], aB, 3072);
            DSR(av[0], aA, 0); DSR(av[1], aA, 1024); DSR(av[2], aA, 2048); DSR(av[3], aA, 3072);
        }
        if (t + 2 < ks) SG(t + 2);                    // overwrites slot last read in t-1
        LGKMN(2);
        __builtin_amdgcn_s_setprio(1);
        #pragma unroll
        for (int m = 0; m < 2; ++m)
            #pragma unroll
            for (int n = 0; n < 4; ++n)
                acc[m][n] = __builtin_amdgcn_mfma_f32_16x16x32_bf16(av[m], bv[n], acc[m][n], 0, 0, 0);
        __builtin_amdgcn_s_setprio(0);
        LGKMN(0);
        __builtin_amdgcn_s_setprio(1);
        #pragma unroll
        for (int m = 2; m < 4; ++m)
            #pragma unroll
            for (int n = 0; n < 4; ++n)
                acc[m][n] = __builtin_amdgcn_mfma_f32_16x16x32_bf16(av[m], bv[n], acc[m][n], 0, 0, 0);
        __builtin_amdgcn_s_setprio(0);
        if (t + 2 < ks) { WVM(3); } else if (t + 1 < ks) { WVM(0); }
        BAR;
    }

    const int rb = tM * 256 + wr * 64 + ((lane >> 4) << 2);
    const int cb = tN * 128 + wc * 64 + l15;
    if (cf32) {
        float* C = (float*)Cv + (size_t)batch * sCb;
        #pragma unroll
        for (int m = 0; m < 4; ++m)
            #pragma unroll
            for (int n = 0; n < 4; ++n)
                #pragma unroll
                for (int j = 0; j < 4; ++j)
                    C[(size_t)(rb + m * 16 + j) * ldc + cb + n * 16] = acc[m][n][j];
    } else {
        float bb[4] = {0.f, 0.f, 0.f, 0.f};
        if (bias) {
            #pragma unroll
            for (int n = 0; n < 4; ++n) bb[n] = bias[cb + n * 16];
        }
        u16* C = (u16*)Cv + (size_t)batch * sCb;
        #pragma unroll
        for (int m = 0; m < 4; ++m)
            #pragma unroll
            for (int n = 0; n < 4; ++n)
                #pragma unroll
                for (int j = 0; j < 4; ++j)
                    C[(size_t)(rb + m * 16 + j) * ldc + cb + n * 16] = f2bf(acc[m][n][j] + bb[n]);
    }
}

// ---------- GEMM3: BM=BN=128, 3-barrier K-tile, fused output epilogue ----------
__global__ __launch_bounds__(512, 4) void k_g3(const u16* __restrict__ A, int lda,
                                               const u16* __restrict__ Bt,
                                               const float* __restrict__ anchors,
                                               const float* __restrict__ cls_b,
                                               const float* __restrict__ reg_b,
                                               float* __restrict__ out,
                                               int nwg, int ks) {
    __shared__ __attribute__((aligned(16))) u16 LDS[32768];
    const int bid = blockIdx.x;
    const int cpx = nwg >> 3;
    const int tM = (bid & 7) * cpx + (bid >> 3);
    const int tid = threadIdx.x;
    const int lane = tid & 63, w = tid >> 6;
    const int wr2 = w >> 2, wc2 = w & 3;
    const int l15 = lane & 15;
    const int lkswz = ((lane >> 4) ^ ((l15 >> 1) & 3)) * 8;
    const u16* Abase = A + (size_t)tM * 128 * lda;
    const int srow = tid >> 2;
    const int sgc = (((tid & 3) ^ ((tid >> 3) & 3)) * 8);

    f32x4 acc[4][2] = {};

    auto SGA = [&](int t, int kh) {
        const int base = ((t & 1) * 2 + kh) * 4096;
        gload16(Abase + (size_t)srow * lda + t * 64 + kh * 32 + sgc, &LDS[base + tid * 8]);
    };
    auto SGB = [&](int t, int kh) {
        const int base = 16384 + ((t & 1) * 2 + kh) * 4096;
        gload16(Bt + (size_t)srow * 1536 + t * 64 + kh * 32 + sgc, &LDS[base + tid * 8]);
    };

    SGA(0, 0); SGB(0, 0); SGA(0, 1); SGB(0, 1);
    if (ks > 1) { SGA(1, 0); SGB(1, 0); WVM(2); } else { WVM(0); }
    BAR;

    const unsigned aAl = (unsigned)(size_t)&LDS[(wr2 * 64 + l15) * 32 + lkswz];
    const unsigned aBl = (unsigned)(size_t)&LDS[16384 + (wc2 * 32 + l15) * 32 + lkswz];

    #define G3MF(i0, i1, A0, A1, B) do { \
        __builtin_amdgcn_s_setprio(1); \
        acc[i0][0] = __builtin_amdgcn_mfma_f32_16x16x32_bf16(A0, B[0], acc[i0][0], 0, 0, 0); \
        acc[i0][1] = __builtin_amdgcn_mfma_f32_16x16x32_bf16(A0, B[1], acc[i0][1], 0, 0, 0); \
        acc[i1][0] = __builtin_amdgcn_mfma_f32_16x16x32_bf16(A1, B[0], acc[i1][0], 0, 0, 0); \
        acc[i1][1] = __builtin_amdgcn_mfma_f32_16x16x32_bf16(A1, B[1], acc[i1][1], 0, 0, 0); \
        __builtin_amdgcn_s_setprio(0); } while (0)

    for (int t = 0; t < ks; ++t) {
        const unsigned bo = (unsigned)(t & 1) * 16384u;
        short8 a0, a1, a2, a3, bb[2];
        if (t + 1 < ks) { SGA(t + 1, 1); SGB(t + 1, 1); }
        {
            unsigned aA = aAl + bo, aB = aBl + bo;
            DSR(bb[0], aB, 0); DSR(bb[1], aB, 1024);
            DSR(a0, aA, 0); DSR(a1, aA, 1024);
            DSR(a2, aA, 2048); DSR(a3, aA, 3072);
        }
        LGKMN(2);
        G3MF(0, 1, a0, a1, bb);
        LGKMN(0);
        BAR;
        if (t + 2 < ks) SGA(t + 2, 0);
        G3MF(2, 3, a2, a3, bb);
        {
            unsigned aA = aAl + bo + 8192u, aB = aBl + bo + 8192u;
            DSR(bb[0], aB, 0); DSR(bb[1], aB, 1024);
            DSR(a0, aA, 0); DSR(a1, aA, 1024);
            DSR(a2, aA, 2048); DSR(a3, aA, 3072);
        }
        LGKMN(2);
        G3MF(0, 1, a0, a1, bb);
        LGKMN(0);
        BAR;
        if (t + 2 < ks) SGB(t + 2, 0);
        G3MF(2, 3, a2, a3, bb);
        if (t + 2 < ks) { WVM(2); } else if (t + 1 < ks) { WVM(0); }
        BAR;
    }
    #undef G3MF

    const int rb = tM * 128 + wr2 * 64 + ((lane >> 4) << 2);
    const int o = wc2 * 32 + l15;
    #pragma unroll
    for (int m = 0; m < 4; ++m) {
        #pragma unroll
        for (int n = 0; n < 2; ++n) {
            int oc = o + n * 16;
            #pragma unroll
            for (int j = 0; j < 4; ++j) {
                int r = rb + m * 16 + j;
                int b = r >> 10, nn = r & 1023;
                if (nn < 1000) {
                    float v = acc[m][n][j];
                    float* orow = out + ((size_t)b * 1000 + nn) * 77;
                    if (oc < 2) {
                        orow[oc] = v + cls_b[oc];
                    } else if (oc < 75) {
                        orow[oc + 2] = v + reg_b[oc - 2] + anchors[nn * 77 + oc + 2];
                        if (oc == 2) orow[2] = anchors[nn * 77 + 2];
                        if (oc == 3) orow[3] = anchors[nn * 77 + 3];
                    }
                }
            }
        }
    }
}

// ---------- softmax + diagonal-shift: wave-per-row, no barriers, no LDS ----------
__global__ __launch_bounds__(256) void k_softmax(u16* __restrict__ att) {
    const int tid = threadIdx.x;
    const int lane = tid & 63;
    const int w = blockIdx.x * 4 + (tid >> 6);       // 0..7999
    const int co0 = lane * 8, co1 = 512 + lane * 8;

    short8 c0, c1;
    {
        int b = w / 1000, n = w - b * 1000;
        const u16* rp = att + ((size_t)(b * 1024 + n)) * 1024;
        c0 = *(const short8*)&rp[co0];
        c1 = *(const short8*)&rp[co1];
    }
    for (int k = 0; k < 4; ++k) {
        const int idx = w + k * 8000;
        const int b = idx / 1000, n = idx - b * 1000;
        u16* rp = att + ((size_t)(b * 1024 + n)) * 1024;
        short8 d0 = c0, d1 = c1;
        if (k < 3) {
            int i2 = w + (k + 1) * 8000;
            int b2 = i2 / 1000, n2 = i2 - b2 * 1000;
            const u16* rp2 = att + ((size_t)(b2 * 1024 + n2)) * 1024;
            c0 = *(const short8*)&rp2[co0];
            c1 = *(const short8*)&rp2[co1];
        }
        float f0[8], f1[8];
        float m = -1e30f;
        #pragma unroll
        for (int j = 0; j < 8; ++j) {
            f0[j] = bf2f((u16)d0[j]);
            m = fmaxf(m, f0[j]);
        }
        #pragma unroll
        for (int j = 0; j < 8; ++j) {
            f1[j] = (co1 + j < 999) ? bf2f((u16)d1[j]) : -1e30f;
            m = fmaxf(m, f1[j]);
        }
        #pragma unroll
        for (int o = 32; o > 0; o >>= 1) m = fmaxf(m, __shfl_xor(m, o));
        float e0[8], e1[8];
        float s = 0.f;
        #pragma unroll
        for (int j = 0; j < 8; ++j) { e0[j] = __expf(f0[j] - m); s += e0[j]; }
        #pragma unroll
        for (int j = 0; j < 8; ++j) {
            e1[j] = (co1 + j < 999) ? __expf(f1[j] - m) : 0.f;
            s += e1[j];
        }
        #pragma unroll
        for (int o = 32; o > 0; o >>= 1) s += __shfl_xor(s, o);
        const float inv = 1.f / s;
        float p0 = __shfl_up(e0[7], 1);
        float p1 = __shfl_up(e1[7], 1);
        float x63 = __shfl(e0[7], 63);
        if (lane == 0) p1 = x63;
        short8 o0, o1;
        #pragma unroll
        for (int j = 0; j < 8; ++j) {
            int c = co0 + j;
            float pm = (j == 0) ? p0 : e0[j - 1];
            float val = (c < n) ? e0[j] : ((c > n) ? pm : 0.f);
            o0[j] = (short)f2bf(val * inv);
        }
        #pragma unroll
        for (int j = 0; j < 8; ++j) {
            int c = co1 + j;
            float pm = (j == 0) ? p1 : e1[j - 1];
            float val = 0.f;
            if (c < 1000) val = (c < n) ? e1[j] : ((c > n) ? pm : 0.f);
            o1[j] = (short)f2bf(val * inv);
        }
        *(short8*)&rp[co0] = o0;
        *(short8*)&rp[co1] = o1;
    }
}

extern "C" void kernel_launch(void* const* d_in, const int* in_sizes, int n_in,
                              void* d_out, int out_size, void* d_ws, size_t ws_size,
                              hipStream_t stream) {
    const float* x       = (const float*)d_in[0];
    const float* anchors = (const float*)d_in[1];
    const float* conv1_w = (const float*)d_in[2];
    const float* conv1_b = (const float*)d_in[3];
    const float* attn_w  = (const float*)d_in[4];
    const float* attn_b  = (const float*)d_in[5];
    const float* cls_w   = (const float*)d_in[6];
    const float* cls_b   = (const float*)d_in[7];
    const float* reg_w   = (const float*)d_in[8];
    const float* reg_b   = (const float*)d_in[9];
    const int*   cut_xs  = (const int*)d_in[12];
    const void*  invalid = d_in[13];
    float* out = (float*)d_out;

    char* ws = (char*)d_ws;
    u16*   wcat    = (u16*)  (ws + 0);           // 128x1536
    u16*   attn_wb = (u16*)  (ws + 393216);
    u16*   af      = (u16*)  (ws + 1835008);     // [32][1024][1536]
    u16*   bafT    = (u16*)  (ws + 102498304);
    u16*   att     = (u16*)  (ws + 152829952);
    float* feat    = (float*)(ws + 152829952);   // inside att, dead before G1
    int*   xn      = (int*)  (ws + 154632192);   // inside att
    float* attn_bp = (float*)(ws + 219938816);   // 1024 f32

    k_prep<<<2071, 512, 0, stream>>>(attn_w, cls_w, reg_w, cut_xs, invalid, attn_b,
                                     x, conv1_w, conv1_b,
                                     attn_wb, wcat, xn, attn_bp, feat);
    k_gat<<<dim3(192, 32), 256, 0, stream>>>(feat, xn, af, bafT);
    // G1: att = af_hi(32768x704,lda1536) x attn_wb(1024x704)^T + attn_bp
    k_g8<<<1024, 512, 0, stream>>>(af + 768, 0L, 1536, attn_wb, 0L, 704,
                                   att, 0L, 1024, 8, 1024, 1024, 22, 0, attn_bp);
    k_softmax<<<2000, 256, 0, stream>>>(att);
    // G2 (batched 32): af_lo = att(1024x1024) x bafT(768x1024)^T ; 4x6 tiles, ks=32
    k_g8<<<768, 512, 0, stream>>>(att, 1048576L, 1024, bafT, 786432L, 1024,
                                  af, 1572864L, 1536, 6, 24, 768, 32, 0, nullptr);
    // G3: out = epilogue(af(32768x1536) x wcat(128x1536)^T)
    k_g3<<<256, 512, 0, stream>>>(af, 1536, wcat, anchors, cls_b, reg_b, out, 256, 24);
}

// Round 18
// 218.452 us; speedup vs baseline: 1.2100x; 1.2100x over previous
//
#include <hip/hip_runtime.h>

// LaneATT head, MI355X.
// all_feat af[b][1024][1536] bf16: cols 0:768 = att_feat (GEMM2 C), 768:1536 = baf (gather).
// wcat is 128x1536 matching af col geometry (k 704..767 and 1472..1535 zero).
// Pipeline (6 dispatches): k_prep(prep+biaspad+conv, 512thr) -> k_gat(gather+transpose)
//  -> G1=k_g8(af_hi x attn_wb^T + attn_b -> att) -> softmax(wave-per-row)
//  -> G2=k_g8(att x bafT^T -> af_lo) -> G3=k_g3 (fused epilogue).
// k_g8 (measured-best): BM=256 BN=128 BK=32, 3-slot LDS ring (72KB -> 2 blocks/CU,
//  4 waves/SIMD), 1 barrier + counted vmcnt(3) per K-tile (never 0 in steady state).
// Conv history: r16 LDS [o][c] scalar-broadcast = ~55us ; r17 global-weights = 78us
//  (compiler does NOT scalarize runtime-pointer loads) ; r18 = LDS c-major float4
//  broadcast (1 ds_read_b128 + 4 FMA per c) + og split 8->16 (2 conv blocks/CU).
// ws layout: wcat @0 (393,216) | attn_wb @393,216 (1,441,792) | af @1,835,008 (100,663,296)
//  | bafT @102,498,304 (50,331,648) | att @152,829,952 (67,108,864; feat f32 + xn live
//  pre-G1) | attn_bp @219,938,816 (4,096). End 219,942,912.

typedef unsigned short u16;
typedef short short8 __attribute__((ext_vector_type(8)));
typedef float f32x4 __attribute__((ext_vector_type(4)));

__device__ __forceinline__ u16 f2bf(float f) {
    union { float f; unsigned u; } v; v.f = f;
    unsigned r = v.u + 0x7FFFu + ((v.u >> 16) & 1u);
    return (u16)(r >> 16);
}
__device__ __forceinline__ float bf2f(u16 u) {
    union { unsigned u; float f; } v; v.u = ((unsigned)u) << 16;
    return v.f;
}

__device__ __forceinline__ void gload16(const u16* gsrc, u16* ldst) {
    __builtin_amdgcn_global_load_lds(
        (const __attribute__((address_space(1))) unsigned int*)gsrc,
        (__attribute__((address_space(3))) unsigned int*)ldst, 16, 0, 0);
}

#define DSR(d, a, off) asm volatile("ds_read_b128 %0, %1 offset:" #off : "=v"(d) : "v"(a))
#define LGKMN(n) do { asm volatile("s_waitcnt lgkmcnt(" #n ")" ::: "memory"); \
                      __builtin_amdgcn_sched_barrier(0); } while (0)
#define WVM(n) do { asm volatile("s_waitcnt vmcnt(" #n ")" ::: "memory"); \
                    __builtin_amdgcn_sched_barrier(0); } while (0)
#define BAR do { __builtin_amdgcn_s_barrier(); \
                 __builtin_amdgcn_sched_barrier(0); } while (0)

// ---------- fused prep + conv (512 threads):
// [0,1408) attnw | [1408,1792) wcat | [1792,1814) xn | 1814 biaspad | [1815,2327) conv
__global__ __launch_bounds__(512) void k_prep(const float* __restrict__ attn_w,
                                              const float* __restrict__ cls_w,
                                              const float* __restrict__ reg_w,
                                              const int* __restrict__ cut_xs,
                                              const void* __restrict__ mask,
                                              const float* __restrict__ attn_b,
                                              const float* __restrict__ x,
                                              const float* __restrict__ w1,
                                              const float* __restrict__ b1,
                                              u16* __restrict__ attn_wb,
                                              u16* __restrict__ wcat,
                                              int* __restrict__ xn,
                                              float* __restrict__ attn_bp,
                                              float* __restrict__ feat) {
    const int blk = blockIdx.x, tid = threadIdx.x;
    if (blk < 1408) {
        int i = blk * 512 + tid;                    // 1024*704 = 720896 exactly
        int r = i / 704;
        attn_wb[i] = (r < 999) ? f2bf(attn_w[i]) : (u16)0;
        return;
    }
    if (blk < 1792) {
        int i = (blk - 1408) * 512 + tid;           // 128*1536 = 196608 exactly
        int o = i / 1536, k = i - o * 1536;
        int ksrc = -1;
        if (k < 704) ksrc = k;
        else if (k >= 768 && k < 1472) ksrc = k - 64;
        float v = 0.f;
        if (ksrc >= 0) {
            if (o < 2) v = cls_w[o * 1408 + ksrc];
            else if (o < 75) v = reg_w[(o - 2) * 1408 + ksrc];
        }
        wcat[i] = f2bf(v);
        return;
    }
    if (blk < 1814) {
        const unsigned char* m8 = (const unsigned char*)mask;
        int any = 0;
        for (int i = tid; i < 11000; i += 512)
            if ((i & 3) && m8[i]) any = 1;
        any = __any(any) ? 1 : 0;
        __shared__ int sh[8];
        if ((tid & 63) == 0) sh[tid >> 6] = any;
        __syncthreads();
        int isb8 = 0;
        #pragma unroll
        for (int q = 0; q < 8; ++q) isb8 |= sh[q];
        int i = (blk - 1792) * 512 + tid;
        if (i < 11000) {
            int inv = isb8 ? (int)m8[i] : ((const int*)mask)[i];
            int n = i / 11, y = i - n * 11;
            xn[i] = inv ? -1 : cut_xs[n * 704 + y];
        }
        return;
    }
    if (blk == 1814) {
        for (int c = tid; c < 1024; c += 512)
            attn_bp[c] = (c < 999) ? attn_b[c] : 0.f;
        return;
    }
    // conv 1x1: idx -> (b, og of 4 out-ch); thread = (pixel p, K-half kh).
    // Weights staged c-major: one broadcast ds_read_b128 -> 4 weights per c,
    // so per c-iter = 1 coalesced x load + 1 LDS read + 4 FMA.
    {
        __shared__ __attribute__((aligned(16))) float wlT[512][4];  // [c][o]
        __shared__ float part[4][224];
        const int idx = blk - 1815;
        const int b = idx & 31, og = idx >> 5;       // og 0..15
        for (int i = tid; i < 2048; i += 512) {
            int c = i >> 2, o = i & 3;
            wlT[c][o] = w1[(size_t)(og * 4 + o) * 512 + c];
        }
        __syncthreads();
        const int p = tid & 255, kh = tid >> 8;
        f32x4 acc = {0.f, 0.f, 0.f, 0.f};
        if (p < 220) {
            const float* xb = x + (size_t)b * 512 * 220 + kh * 256 * 220 + p;
            const f32x4* wv = (const f32x4*)&wlT[kh * 256][0];
            #pragma unroll 8
            for (int c = 0; c < 256; ++c) {
                float xv = xb[(size_t)c * 220];
                f32x4 wq = wv[c];
                acc[0] = fmaf(xv, wq[0], acc[0]);
                acc[1] = fmaf(xv, wq[1], acc[1]);
                acc[2] = fmaf(xv, wq[2], acc[2]);
                acc[3] = fmaf(xv, wq[3], acc[3]);
            }
        }
        if (kh == 1 && p < 220) {
            #pragma unroll
            for (int o = 0; o < 4; ++o) part[o][p] = acc[o];
        }
        __syncthreads();
        if (kh == 0 && p < 220) {
            float* fo = feat + (size_t)b * 14080 + (og * 4) * 220 + p;
            #pragma unroll
            for (int o = 0; o < 4; ++o)
                fo[(size_t)o * 220] = acc[o] + part[o][p] + b1[og * 4 + o];
        }
    }
}

// ---------- fused gather + transpose ----------
__global__ __launch_bounds__(256) void k_gat(const float* __restrict__ feat,
                                             const int* __restrict__ xn,
                                             u16* __restrict__ af,
                                             u16* __restrict__ bafT) {
    __shared__ __attribute__((aligned(16))) u16 tl[64 * 64];
    const int mt = blockIdx.x & 15, dt = blockIdx.x >> 4;
    const int b = blockIdx.y;
    const int tid = threadIdx.x;
    const float* fb = feat + (size_t)b * 14080;
    #pragma unroll
    for (int h = 0; h < 2; ++h) {
        const int nl = (tid >> 3) + h * 32;
        const int n = mt * 64 + nl;
        const int dc = (tid & 7) * 8;
        const int d8 = dt * 64 + dc;
        short8 o = {0, 0, 0, 0, 0, 0, 0, 0};
        #pragma unroll
        for (int j = 0; j < 8; ++j) {
            int d = d8 + j;
            float v = 0.f;
            if (n < 1000 && d < 704) {
                int c = d / 11, y = d - c * 11;
                int xv = xn[n * 11 + y];
                if (xv >= 0) v = fb[c * 220 + y * 20 + xv];
            }
            o[j] = (short)f2bf(v);
        }
        *(short8*)&af[((size_t)(b * 1024 + n)) * 1536 + 768 + d8] = o;
        int key = ((nl >> 3) + nl) & 7;
        *(short8*)&tl[nl * 64 + (((tid & 7) ^ key) * 8)] = o;
    }
    __syncthreads();
    u16* dst = bafT + ((size_t)b * 768 + dt * 64) * 1024 + mt * 64;
    #pragma unroll
    for (int h = 0; h < 2; ++h) {
        int slot = h * 256 + tid;
        int dl = slot >> 3, m8 = (slot & 7) * 8;
        short8 v;
        #pragma unroll
        for (int j = 0; j < 8; ++j) {
            int m = m8 + j;
            int key = ((m >> 3) + m) & 7;
            v[j] = (short)tl[m * 64 + (((dl >> 3) ^ key) * 8) + (dl & 7)];
        }
        *(short8*)&dst[(size_t)dl * 1024 + m8] = v;
    }
}

// ---------- GEMM engine (measured-best): BM=256 BN=128 BK=32, ring-3 ----------
__global__ __launch_bounds__(512, 4) void k_g8(const u16* __restrict__ A, long sAb, int lda,
                                               const u16* __restrict__ Bt, long sBb, int ldb,
                                               void* __restrict__ Cv, long sCb, int ldc,
                                               int ntN, int tpb, int nwg, int ks, int cf32,
                                               const float* __restrict__ bias) {
    __shared__ __attribute__((aligned(16))) u16 LDS[36864];   // 72 KB
    const int bid = blockIdx.x;
    const int cpx = nwg >> 3;                         // bijective XCD swizzle (nwg%8==0)
    const int logical = (bid & 7) * cpx + (bid >> 3);
    const int batch = logical / tpb;
    const int t0 = logical - batch * tpb;
    const int tM = t0 / ntN, tN = t0 - tM * ntN;
    A  += (size_t)batch * sAb;
    Bt += (size_t)batch * sBb;

    const int tid = threadIdx.x;
    const int lane = tid & 63, w = tid >> 6;
    const int wr = w >> 1, wc = w & 1;                // wave tile: rows wr*64, cols wc*64
    const int l15 = lane & 15;
    const int lkswz = ((lane >> 4) ^ ((l15 >> 1) & 3)) * 8;
    const u16* Abase = A + (size_t)tM * 256 * lda;
    const u16* Bbase = Bt + (size_t)tN * 128 * ldb;
    const int srow = tid >> 2;
    const int sgc = (((tid & 3) ^ ((tid >> 3) & 3)) * 8);

    f32x4 acc[4][4] = {};

    auto SG = [&](int t) {
        const int s = (t % 3) * 12288;                // slot base (u16)
        const u16* ga = Abase + (size_t)srow * lda + t * 32 + sgc;
        gload16(ga, &LDS[s + tid * 8]);
        gload16(ga + (size_t)128 * lda, &LDS[s + 4096 + tid * 8]);
        gload16(Bbase + (size_t)srow * ldb + t * 32 + sgc, &LDS[s + 8192 + tid * 8]);
    };

    SG(0);
    if (ks > 1) { SG(1); WVM(3); } else { WVM(0); }
    BAR;

    const unsigned aAl = (unsigned)(size_t)&LDS[(wr * 64 + l15) * 32 + lkswz];
    const unsigned aBl = (unsigned)(size_t)&LDS[8192 + (wc * 64 + l15) * 32 + lkswz];

    for (int t = 0; t < ks; ++t) {
        const unsigned sb = (unsigned)(t % 3) * 24576u;
        short8 av[4], bv[4];
        {
            unsigned aA = aAl + sb, aB = aBl + sb;
            DSR(bv[0], aB, 0); DSR(bv[1], aB, 1024); DSR(bv[2], aB, 2048); DSR(bv[3], aB, 3072);
            DSR(av[0], aA, 0); DSR(av[1], aA, 1024); DSR(av[2], aA, 2048); DSR(av[3], aA, 3072);
        }
        if (t + 2 < ks) SG(t + 2);                    // overwrites slot last read in t-1
        LGKMN(2);
        __builtin_amdgcn_s_setprio(1);
        #pragma unroll
        for (int m = 0; m < 2; ++m)
            #pragma unroll
            for (int n = 0; n < 4; ++n)
                acc[m][n] = __builtin_amdgcn_mfma_f32_16x16x32_bf16(av[m], bv[n], acc[m][n], 0, 0, 0);
        __builtin_amdgcn_s_setprio(0);
        LGKMN(0);
        __builtin_amdgcn_s_setprio(1);
        #pragma unroll
        for (int m = 2; m < 4; ++m)
            #pragma unroll
            for (int n = 0; n < 4; ++n)
                acc[m][n] = __builtin_amdgcn_mfma_f32_16x16x32_bf16(av[m], bv[n], acc[m][n], 0, 0, 0);
        __builtin_amdgcn_s_setprio(0);
        if (t + 2 < ks) { WVM(3); } else if (t + 1 < ks) { WVM(0); }
        BAR;
    }

    const int rb = tM * 256 + wr * 64 + ((lane >> 4) << 2);
    const int cb = tN * 128 + wc * 64 + l15;
    if (cf32) {
        float* C = (float*)Cv + (size_t)batch * sCb;
        #pragma unroll
        for (int m = 0; m < 4; ++m)
            #pragma unroll
            for (int n = 0; n < 4; ++n)
                #pragma unroll
                for (int j = 0; j < 4; ++j)
                    C[(size_t)(rb + m * 16 + j) * ldc + cb + n * 16] = acc[m][n][j];
    } else {
        float bb[4] = {0.f, 0.f, 0.f, 0.f};
        if (bias) {
            #pragma unroll
            for (int n = 0; n < 4; ++n) bb[n] = bias[cb + n * 16];
        }
        u16* C = (u16*)Cv + (size_t)batch * sCb;
        #pragma unroll
        for (int m = 0; m < 4; ++m)
            #pragma unroll
            for (int n = 0; n < 4; ++n)
                #pragma unroll
                for (int j = 0; j < 4; ++j)
                    C[(size_t)(rb + m * 16 + j) * ldc + cb + n * 16] = f2bf(acc[m][n][j] + bb[n]);
    }
}

// ---------- GEMM3: BM=BN=128, 3-barrier K-tile, fused output epilogue ----------
__global__ __launch_bounds__(512, 4) void k_g3(const u16* __restrict__ A, int lda,
                                               const u16* __restrict__ Bt,
                                               const float* __restrict__ anchors,
                                               const float* __restrict__ cls_b,
                                               const float* __restrict__ reg_b,
                                               float* __restrict__ out,
                                               int nwg, int ks) {
    __shared__ __attribute__((aligned(16))) u16 LDS[32768];
    const int bid = blockIdx.x;
    const int cpx = nwg >> 3;
    const int tM = (bid & 7) * cpx + (bid >> 3);
    const int tid = threadIdx.x;
    const int lane = tid & 63, w = tid >> 6;
    const int wr2 = w >> 2, wc2 = w & 3;
    const int l15 = lane & 15;
    const int lkswz = ((lane >> 4) ^ ((l15 >> 1) & 3)) * 8;
    const u16* Abase = A + (size_t)tM * 128 * lda;
    const int srow = tid >> 2;
    const int sgc = (((tid & 3) ^ ((tid >> 3) & 3)) * 8);

    f32x4 acc[4][2] = {};

    auto SGA = [&](int t, int kh) {
        const int base = ((t & 1) * 2 + kh) * 4096;
        gload16(Abase + (size_t)srow * lda + t * 64 + kh * 32 + sgc, &LDS[base + tid * 8]);
    };
    auto SGB = [&](int t, int kh) {
        const int base = 16384 + ((t & 1) * 2 + kh) * 4096;
        gload16(Bt + (size_t)srow * 1536 + t * 64 + kh * 32 + sgc, &LDS[base + tid * 8]);
    };

    SGA(0, 0); SGB(0, 0); SGA(0, 1); SGB(0, 1);
    if (ks > 1) { SGA(1, 0); SGB(1, 0); WVM(2); } else { WVM(0); }
    BAR;

    const unsigned aAl = (unsigned)(size_t)&LDS[(wr2 * 64 + l15) * 32 + lkswz];
    const unsigned aBl = (unsigned)(size_t)&LDS[16384 + (wc2 * 32 + l15) * 32 + lkswz];

    #define G3MF(i0, i1, A0, A1, B) do { \
        __builtin_amdgcn_s_setprio(1); \
        acc[i0][0] = __builtin_amdgcn_mfma_f32_16x16x32_bf16(A0, B[0], acc[i0][0], 0, 0, 0); \
        acc[i0][1] = __builtin_amdgcn_mfma_f32_16x16x32_bf16(A0, B[1], acc[i0][1], 0, 0, 0); \
        acc[i1][0] = __builtin_amdgcn_mfma_f32_16x16x32_bf16(A1, B[0], acc[i1][0], 0, 0, 0); \
        acc[i1][1] = __builtin_amdgcn_mfma_f32_16x16x32_bf16(A1, B[1], acc[i1][1], 0, 0, 0); \
        __builtin_amdgcn_s_setprio(0); } while (0)

    for (int t = 0; t < ks; ++t) {
        const unsigned bo = (unsigned)(t & 1) * 16384u;
        short8 a0, a1, a2, a3, bb[2];
        if (t + 1 < ks) { SGA(t + 1, 1); SGB(t + 1, 1); }
        {
            unsigned aA = aAl + bo, aB = aBl + bo;
            DSR(bb[0], aB, 0); DSR(bb[1], aB, 1024);
            DSR(a0, aA, 0); DSR(a1, aA, 1024);
            DSR(a2, aA, 2048); DSR(a3, aA, 3072);
        }
        LGKMN(2);
        G3MF(0, 1, a0, a1, bb);
        LGKMN(0);
        BAR;
        if (t + 2 < ks) SGA(t + 2, 0);
        G3MF(2, 3, a2, a3, bb);
        {
            unsigned aA = aAl + bo + 8192u, aB = aBl + bo + 8192u;
            DSR(bb[0], aB, 0); DSR(bb[1], aB, 1024);
            DSR(a0, aA, 0); DSR(a1, aA, 1024);
            DSR(a2, aA, 2048); DSR(a3, aA, 3072);
        }
        LGKMN(2);
        G3MF(0, 1, a0, a1, bb);
        LGKMN(0);
        BAR;
        if (t + 2 < ks) SGB(t + 2, 0);
        G3MF(2, 3, a2, a3, bb);
        if (t + 2 < ks) { WVM(2); } else if (t + 1 < ks) { WVM(0); }
        BAR;
    }
    #undef G3MF

    const int rb = tM * 128 + wr2 * 64 + ((lane >> 4) << 2);
    const int o = wc2 * 32 + l15;
    #pragma unroll
    for (int m = 0; m < 4; ++m) {
        #pragma unroll
        for (int n = 0; n < 2; ++n) {
            int oc = o + n * 16;
            #pragma unroll
            for (int j = 0; j < 4; ++j) {
                int r = rb + m * 16 + j;
                int b = r >> 10, nn = r & 1023;
                if (nn < 1000) {
                    float v = acc[m][n][j];
                    float* orow = out + ((size_t)b * 1000 + nn) * 77;
                    if (oc < 2) {
                        orow[oc] = v + cls_b[oc];
                    } else if (oc < 75) {
                        orow[oc + 2] = v + reg_b[oc - 2] + anchors[nn * 77 + oc + 2];
                        if (oc == 2) orow[2] = anchors[nn * 77 + 2];
                        if (oc == 3) orow[3] = anchors[nn * 77 + 3];
                    }
                }
            }
        }
    }
}

// ---------- softmax + diagonal-shift: wave-per-row, no barriers, no LDS ----------
__global__ __launch_bounds__(256) void k_softmax(u16* __restrict__ att) {
    const int tid = threadIdx.x;
    const int lane = tid & 63;
    const int w = blockIdx.x * 4 + (tid >> 6);       // 0..7999
    const int co0 = lane * 8, co1 = 512 + lane * 8;

    short8 c0, c1;
    {
        int b = w / 1000, n = w - b * 1000;
        const u16* rp = att + ((size_t)(b * 1024 + n)) * 1024;
        c0 = *(const short8*)&rp[co0];
        c1 = *(const short8*)&rp[co1];
    }
    for (int k = 0; k < 4; ++k) {
        const int idx = w + k * 8000;
        const int b = idx / 1000, n = idx - b * 1000;
        u16* rp = att + ((size_t)(b * 1024 + n)) * 1024;
        short8 d0 = c0, d1 = c1;
        if (k < 3) {
            int i2 = w + (k + 1) * 8000;
            int b2 = i2 / 1000, n2 = i2 - b2 * 1000;
            const u16* rp2 = att + ((size_t)(b2 * 1024 + n2)) * 1024;
            c0 = *(const short8*)&rp2[co0];
            c1 = *(const short8*)&rp2[co1];
        }
        float f0[8], f1[8];
        float m = -1e30f;
        #pragma unroll
        for (int j = 0; j < 8; ++j) {
            f0[j] = bf2f((u16)d0[j]);
            m = fmaxf(m, f0[j]);
        }
        #pragma unroll
        for (int j = 0; j < 8; ++j) {
            f1[j] = (co1 + j < 999) ? bf2f((u16)d1[j]) : -1e30f;
            m = fmaxf(m, f1[j]);
        }
        #pragma unroll
        for (int o = 32; o > 0; o >>= 1) m = fmaxf(m, __shfl_xor(m, o));
        float e0[8], e1[8];
        float s = 0.f;
        #pragma unroll
        for (int j = 0; j < 8; ++j) { e0[j] = __expf(f0[j] - m); s += e0[j]; }
        #pragma unroll
        for (int j = 0; j < 8; ++j) {
            e1[j] = (co1 + j < 999) ? __expf(f1[j] - m) : 0.f;
            s += e1[j];
        }
        #pragma unroll
        for (int o = 32; o > 0; o >>= 1) s += __shfl_xor(s, o);
        const float inv = 1.f / s;
        float p0 = __shfl_up(e0[7], 1);
        float p1 = __shfl_up(e1[7], 1);
        float x63 = __shfl(e0[7], 63);
        if (lane == 0) p1 = x63;
        short8 o0, o1;
        #pragma unroll
        for (int j = 0; j < 8; ++j) {
            int c = co0 + j;
            float pm = (j == 0) ? p0 : e0[j - 1];
            float val = (c < n) ? e0[j] : ((c > n) ? pm : 0.f);
            o0[j] = (short)f2bf(val * inv);
        }
        #pragma unroll
        for (int j = 0; j < 8; ++j) {
            int c = co1 + j;
            float pm = (j == 0) ? p1 : e1[j - 1];
            float val = 0.f;
            if (c < 1000) val = (c < n) ? e1[j] : ((c > n) ? pm : 0.f);
            o1[j] = (short)f2bf(val * inv);
        }
        *(short8*)&rp[co0] = o0;
        *(short8*)&rp[co1] = o1;
    }
}

extern "C" void kernel_launch(void* const* d_in, const int* in_sizes, int n_in,
                              void* d_out, int out_size, void* d_ws, size_t ws_size,
                              hipStream_t stream) {
    const float* x       = (const float*)d_in[0];
    const float* anchors = (const float*)d_in[1];
    const float* conv1_w = (const float*)d_in[2];
    const float* conv1_b = (const float*)d_in[3];
    const float* attn_w  = (const float*)d_in[4];
    const float* attn_b  = (const float*)d_in[5];
    const float* cls_w   = (const float*)d_in[6];
    const float* cls_b   = (const float*)d_in[7];
    const float* reg_w   = (const float*)d_in[8];
    const float* reg_b   = (const float*)d_in[9];
    const int*   cut_xs  = (const int*)d_in[12];
    const void*  invalid = d_in[13];
    float* out = (float*)d_out;

    char* ws = (char*)d_ws;
    u16*   wcat    = (u16*)  (ws + 0);           // 128x1536
    u16*   attn_wb = (u16*)  (ws + 393216);
    u16*   af      = (u16*)  (ws + 1835008);     // [32][1024][1536]
    u16*   bafT    = (u16*)  (ws + 102498304);
    u16*   att     = (u16*)  (ws + 152829952);
    float* feat    = (float*)(ws + 152829952);   // inside att, dead before G1
    int*   xn      = (int*)  (ws + 154632192);   // inside att
    float* attn_bp = (float*)(ws + 219938816);   // 1024 f32

    k_prep<<<2327, 512, 0, stream>>>(attn_w, cls_w, reg_w, cut_xs, invalid, attn_b,
                                     x, conv1_w, conv1_b,
                                     attn_wb, wcat, xn, attn_bp, feat);
    k_gat<<<dim3(192, 32), 256, 0, stream>>>(feat, xn, af, bafT);
    // G1: att = af_hi(32768x704,lda1536) x attn_wb(1024x704)^T + attn_bp
    k_g8<<<1024, 512, 0, stream>>>(af + 768, 0L, 1536, attn_wb, 0L, 704,
                                   att, 0L, 1024, 8, 1024, 1024, 22, 0, attn_bp);
    k_softmax<<<2000, 256, 0, stream>>>(att);
    // G2 (batched 32): af_lo = att(1024x1024) x bafT(768x1024)^T ; 4x6 tiles, ks=32
    k_g8<<<768, 512, 0, stream>>>(att, 1048576L, 1024, bafT, 786432L, 1024,
                                  af, 1572864L, 1536, 6, 24, 768, 32, 0, nullptr);
    // G3: out = epilogue(af(32768x1536) x wcat(128x1536)^T)
    k_g3<<<256, 512, 0, stream>>>(af, 1536, wcat, anchors, cls_b, reg_b, out, 256, 24);
}

// Round 19
// 215.255 us; speedup vs baseline: 1.2279x; 1.0149x over previous
//
#include <hip/hip_runtime.h>

// LaneATT head, MI355X.
// all_feat af[b][1024][1536] bf16: cols 0:768 = att_feat (GEMM2 C), 768:1536 = baf (gather).
// wcat is 128x1536 matching af col geometry (k 704..767 and 1472..1535 zero).
// Pipeline (6 dispatches): k_prep(prep+biaspad+conv, 512thr) -> k_gat(gather+transpose)
//  -> G1=k_g8(af_hi x attn_wb^T + attn_b -> att) -> softmax(wave-per-row)
//  -> G2=k_g8(att x bafT^T -> af_lo) -> G3=k_g3 (fused epilogue).
// k_g8 (measured-best): BM=256 BN=128 BK=32, 3-slot LDS ring (72KB -> 2 blocks/CU,
//  4 waves/SIMD), 1 barrier + counted vmcnt(3) per K-tile (never 0 in steady state).
// k_g3 (r19): 1024 thr, 16 waves of 32x32 (4 waves/SIMD), A/B staging split by
//  thread-half (1 load/thread per SG, vmcnt(1) counted), zero-pad K-tiles 11 & 23
//  skipped via phys = t + (t>=11), ks=22.
// Conv history: r16 LDS [o][c] scalar-broadcast ~55us ; r17 global-weights 78us ;
//  r18 LDS c-major float4 broadcast = fixed.
// ws layout: wcat @0 (393,216) | attn_wb @393,216 (1,441,792) | af @1,835,008 (100,663,296)
//  | bafT @102,498,304 (50,331,648) | att @152,829,952 (67,108,864; feat f32 + xn live
//  pre-G1) | attn_bp @219,938,816 (4,096). End 219,942,912.

typedef unsigned short u16;
typedef short short8 __attribute__((ext_vector_type(8)));
typedef float f32x4 __attribute__((ext_vector_type(4)));

__device__ __forceinline__ u16 f2bf(float f) {
    union { float f; unsigned u; } v; v.f = f;
    unsigned r = v.u + 0x7FFFu + ((v.u >> 16) & 1u);
    return (u16)(r >> 16);
}
__device__ __forceinline__ float bf2f(u16 u) {
    union { unsigned u; float f; } v; v.u = ((unsigned)u) << 16;
    return v.f;
}

__device__ __forceinline__ void gload16(const u16* gsrc, u16* ldst) {
    __builtin_amdgcn_global_load_lds(
        (const __attribute__((address_space(1))) unsigned int*)gsrc,
        (__attribute__((address_space(3))) unsigned int*)ldst, 16, 0, 0);
}

#define DSR(d, a, off) asm volatile("ds_read_b128 %0, %1 offset:" #off : "=v"(d) : "v"(a))
#define LGKMN(n) do { asm volatile("s_waitcnt lgkmcnt(" #n ")" ::: "memory"); \
                      __builtin_amdgcn_sched_barrier(0); } while (0)
#define WVM(n) do { asm volatile("s_waitcnt vmcnt(" #n ")" ::: "memory"); \
                    __builtin_amdgcn_sched_barrier(0); } while (0)
#define BAR do { __builtin_amdgcn_s_barrier(); \
                 __builtin_amdgcn_sched_barrier(0); } while (0)

// ---------- fused prep + conv (512 threads):
// [0,1408) attnw | [1408,1792) wcat | [1792,1814) xn | 1814 biaspad | [1815,2327) conv
__global__ __launch_bounds__(512) void k_prep(const float* __restrict__ attn_w,
                                              const float* __restrict__ cls_w,
                                              const float* __restrict__ reg_w,
                                              const int* __restrict__ cut_xs,
                                              const void* __restrict__ mask,
                                              const float* __restrict__ attn_b,
                                              const float* __restrict__ x,
                                              const float* __restrict__ w1,
                                              const float* __restrict__ b1,
                                              u16* __restrict__ attn_wb,
                                              u16* __restrict__ wcat,
                                              int* __restrict__ xn,
                                              float* __restrict__ attn_bp,
                                              float* __restrict__ feat) {
    const int blk = blockIdx.x, tid = threadIdx.x;
    if (blk < 1408) {
        int i = blk * 512 + tid;                    // 1024*704 = 720896 exactly
        int r = i / 704;
        attn_wb[i] = (r < 999) ? f2bf(attn_w[i]) : (u16)0;
        return;
    }
    if (blk < 1792) {
        int i = (blk - 1408) * 512 + tid;           // 128*1536 = 196608 exactly
        int o = i / 1536, k = i - o * 1536;
        int ksrc = -1;
        if (k < 704) ksrc = k;
        else if (k >= 768 && k < 1472) ksrc = k - 64;
        float v = 0.f;
        if (ksrc >= 0) {
            if (o < 2) v = cls_w[o * 1408 + ksrc];
            else if (o < 75) v = reg_w[(o - 2) * 1408 + ksrc];
        }
        wcat[i] = f2bf(v);
        return;
    }
    if (blk < 1814) {
        const unsigned char* m8 = (const unsigned char*)mask;
        int any = 0;
        for (int i = tid; i < 11000; i += 512)
            if ((i & 3) && m8[i]) any = 1;
        any = __any(any) ? 1 : 0;
        __shared__ int sh[8];
        if ((tid & 63) == 0) sh[tid >> 6] = any;
        __syncthreads();
        int isb8 = 0;
        #pragma unroll
        for (int q = 0; q < 8; ++q) isb8 |= sh[q];
        int i = (blk - 1792) * 512 + tid;
        if (i < 11000) {
            int inv = isb8 ? (int)m8[i] : ((const int*)mask)[i];
            int n = i / 11, y = i - n * 11;
            xn[i] = inv ? -1 : cut_xs[n * 704 + y];
        }
        return;
    }
    if (blk == 1814) {
        for (int c = tid; c < 1024; c += 512)
            attn_bp[c] = (c < 999) ? attn_b[c] : 0.f;
        return;
    }
    // conv 1x1: idx -> (b, og of 4 out-ch); thread = (pixel p, K-half kh).
    {
        __shared__ __attribute__((aligned(16))) float wlT[512][4];  // [c][o]
        __shared__ float part[4][224];
        const int idx = blk - 1815;
        const int b = idx & 31, og = idx >> 5;       // og 0..15
        for (int i = tid; i < 2048; i += 512) {
            int c = i >> 2, o = i & 3;
            wlT[c][o] = w1[(size_t)(og * 4 + o) * 512 + c];
        }
        __syncthreads();
        const int p = tid & 255, kh = tid >> 8;
        f32x4 acc = {0.f, 0.f, 0.f, 0.f};
        if (p < 220) {
            const float* xb = x + (size_t)b * 512 * 220 + kh * 256 * 220 + p;
            const f32x4* wv = (const f32x4*)&wlT[kh * 256][0];
            #pragma unroll 8
            for (int c = 0; c < 256; ++c) {
                float xv = xb[(size_t)c * 220];
                f32x4 wq = wv[c];
                acc[0] = fmaf(xv, wq[0], acc[0]);
                acc[1] = fmaf(xv, wq[1], acc[1]);
                acc[2] = fmaf(xv, wq[2], acc[2]);
                acc[3] = fmaf(xv, wq[3], acc[3]);
            }
        }
        if (kh == 1 && p < 220) {
            #pragma unroll
            for (int o = 0; o < 4; ++o) part[o][p] = acc[o];
        }
        __syncthreads();
        if (kh == 0 && p < 220) {
            float* fo = feat + (size_t)b * 14080 + (og * 4) * 220 + p;
            #pragma unroll
            for (int o = 0; o < 4; ++o)
                fo[(size_t)o * 220] = acc[o] + part[o][p] + b1[og * 4 + o];
        }
    }
}

// ---------- fused gather + transpose ----------
__global__ __launch_bounds__(256) void k_gat(const float* __restrict__ feat,
                                             const int* __restrict__ xn,
                                             u16* __restrict__ af,
                                             u16* __restrict__ bafT) {
    __shared__ __attribute__((aligned(16))) u16 tl[64 * 64];
    const int mt = blockIdx.x & 15, dt = blockIdx.x >> 4;
    const int b = blockIdx.y;
    const int tid = threadIdx.x;
    const float* fb = feat + (size_t)b * 14080;
    #pragma unroll
    for (int h = 0; h < 2; ++h) {
        const int nl = (tid >> 3) + h * 32;
        const int n = mt * 64 + nl;
        const int dc = (tid & 7) * 8;
        const int d8 = dt * 64 + dc;
        short8 o = {0, 0, 0, 0, 0, 0, 0, 0};
        #pragma unroll
        for (int j = 0; j < 8; ++j) {
            int d = d8 + j;
            float v = 0.f;
            if (n < 1000 && d < 704) {
                int c = d / 11, y = d - c * 11;
                int xv = xn[n * 11 + y];
                if (xv >= 0) v = fb[c * 220 + y * 20 + xv];
            }
            o[j] = (short)f2bf(v);
        }
        *(short8*)&af[((size_t)(b * 1024 + n)) * 1536 + 768 + d8] = o;
        int key = ((nl >> 3) + nl) & 7;
        *(short8*)&tl[nl * 64 + (((tid & 7) ^ key) * 8)] = o;
    }
    __syncthreads();
    u16* dst = bafT + ((size_t)b * 768 + dt * 64) * 1024 + mt * 64;
    #pragma unroll
    for (int h = 0; h < 2; ++h) {
        int slot = h * 256 + tid;
        int dl = slot >> 3, m8 = (slot & 7) * 8;
        short8 v;
        #pragma unroll
        for (int j = 0; j < 8; ++j) {
            int m = m8 + j;
            int key = ((m >> 3) + m) & 7;
            v[j] = (short)tl[m * 64 + (((dl >> 3) ^ key) * 8) + (dl & 7)];
        }
        *(short8*)&dst[(size_t)dl * 1024 + m8] = v;
    }
}

// ---------- GEMM engine (measured-best): BM=256 BN=128 BK=32, ring-3 ----------
__global__ __launch_bounds__(512, 4) void k_g8(const u16* __restrict__ A, long sAb, int lda,
                                               const u16* __restrict__ Bt, long sBb, int ldb,
                                               void* __restrict__ Cv, long sCb, int ldc,
                                               int ntN, int tpb, int nwg, int ks, int cf32,
                                               const float* __restrict__ bias) {
    __shared__ __attribute__((aligned(16))) u16 LDS[36864];   // 72 KB
    const int bid = blockIdx.x;
    const int cpx = nwg >> 3;                         // bijective XCD swizzle (nwg%8==0)
    const int logical = (bid & 7) * cpx + (bid >> 3);
    const int batch = logical / tpb;
    const int t0 = logical - batch * tpb;
    const int tM = t0 / ntN, tN = t0 - tM * ntN;
    A  += (size_t)batch * sAb;
    Bt += (size_t)batch * sBb;

    const int tid = threadIdx.x;
    const int lane = tid & 63, w = tid >> 6;
    const int wr = w >> 1, wc = w & 1;                // wave tile: rows wr*64, cols wc*64
    const int l15 = lane & 15;
    const int lkswz = ((lane >> 4) ^ ((l15 >> 1) & 3)) * 8;
    const u16* Abase = A + (size_t)tM * 256 * lda;
    const u16* Bbase = Bt + (size_t)tN * 128 * ldb;
    const int srow = tid >> 2;
    const int sgc = (((tid & 3) ^ ((tid >> 3) & 3)) * 8);

    f32x4 acc[4][4] = {};

    auto SG = [&](int t) {
        const int s = (t % 3) * 12288;                // slot base (u16)
        const u16* ga = Abase + (size_t)srow * lda + t * 32 + sgc;
        gload16(ga, &LDS[s + tid * 8]);
        gload16(ga + (size_t)128 * lda, &LDS[s + 4096 + tid * 8]);
        gload16(Bbase + (size_t)srow * ldb + t * 32 + sgc, &LDS[s + 8192 + tid * 8]);
    };

    SG(0);
    if (ks > 1) { SG(1); WVM(3); } else { WVM(0); }
    BAR;

    const unsigned aAl = (unsigned)(size_t)&LDS[(wr * 64 + l15) * 32 + lkswz];
    const unsigned aBl = (unsigned)(size_t)&LDS[8192 + (wc * 64 + l15) * 32 + lkswz];

    for (int t = 0; t < ks; ++t) {
        const unsigned sb = (unsigned)(t % 3) * 24576u;
        short8 av[4], bv[4];
        {
            unsigned aA = aAl + sb, aB = aBl + sb;
            DSR(bv[0], aB, 0); DSR(bv[1], aB, 1024); DSR(bv[2], aB, 2048); DSR(bv[3], aB, 3072);
            DSR(av[0], aA, 0); DSR(av[1], aA, 1024); DSR(av[2], aA, 2048); DSR(av[3], aA, 3072);
        }
        if (t + 2 < ks) SG(t + 2);                    // overwrites slot last read in t-1
        LGKMN(2);
        __builtin_amdgcn_s_setprio(1);
        #pragma unroll
        for (int m = 0; m < 2; ++m)
            #pragma unroll
            for (int n = 0; n < 4; ++n)
                acc[m][n] = __builtin_amdgcn_mfma_f32_16x16x32_bf16(av[m], bv[n], acc[m][n], 0, 0, 0);
        __builtin_amdgcn_s_setprio(0);
        LGKMN(0);
        __builtin_amdgcn_s_setprio(1);
        #pragma unroll
        for (int m = 2; m < 4; ++m)
            #pragma unroll
            for (int n = 0; n < 4; ++n)
                acc[m][n] = __builtin_amdgcn_mfma_f32_16x16x32_bf16(av[m], bv[n], acc[m][n], 0, 0, 0);
        __builtin_amdgcn_s_setprio(0);
        if (t + 2 < ks) { WVM(3); } else if (t + 1 < ks) { WVM(0); }
        BAR;
    }

    const int rb = tM * 256 + wr * 64 + ((lane >> 4) << 2);
    const int cb = tN * 128 + wc * 64 + l15;
    if (cf32) {
        float* C = (float*)Cv + (size_t)batch * sCb;
        #pragma unroll
        for (int m = 0; m < 4; ++m)
            #pragma unroll
            for (int n = 0; n < 4; ++n)
                #pragma unroll
                for (int j = 0; j < 4; ++j)
                    C[(size_t)(rb + m * 16 + j) * ldc + cb + n * 16] = acc[m][n][j];
    } else {
        float bb[4] = {0.f, 0.f, 0.f, 0.f};
        if (bias) {
            #pragma unroll
            for (int n = 0; n < 4; ++n) bb[n] = bias[cb + n * 16];
        }
        u16* C = (u16*)Cv + (size_t)batch * sCb;
        #pragma unroll
        for (int m = 0; m < 4; ++m)
            #pragma unroll
            for (int n = 0; n < 4; ++n)
                #pragma unroll
                for (int j = 0; j < 4; ++j)
                    C[(size_t)(rb + m * 16 + j) * ldc + cb + n * 16] = f2bf(acc[m][n][j] + bb[n]);
    }
}

// ---------- GEMM3 (r19): 1024 thr, 16 waves of 32x32, split A/B staging ----------
// out[b][n][77] from af(32768x1536) x wcat(128x1536)^T. BM=128, BK=64 (2 kh of 32).
// Zero-pad K-tiles 11 (704..767) and 23 (1472..1535) skipped: phys = t + (t>=11), ks=22.
// Per thread 1 load per SG (tid<512 -> A, else B): prologue {SG(0,0),SG(0,1),SG(1,0),
// vmcnt(1)}; per tile {SG(t+1,1); dsr kh0; lgkm0; 4 MFMA; BAR; SG(t+2,0); dsr kh1;
// lgkm0; 4 MFMA; vmcnt(1); BAR}. Buffer parity keyed on logical t.
__global__ __launch_bounds__(1024, 4) void k_g3(const u16* __restrict__ A, int lda,
                                                const u16* __restrict__ Bt,
                                                const float* __restrict__ anchors,
                                                const float* __restrict__ cls_b,
                                                const float* __restrict__ reg_b,
                                                float* __restrict__ out,
                                                int nwg) {
    __shared__ __attribute__((aligned(16))) u16 LDS[32768];   // 64 KB: A @0, B @16384
    const int bid = blockIdx.x;
    const int cpx = nwg >> 3;
    const int tM = (bid & 7) * cpx + (bid >> 3);
    const int tid = threadIdx.x;
    const int lane = tid & 63, w = tid >> 6;          // 16 waves
    const int wr2 = w >> 2, wc2 = w & 3;              // wave tile: rows wr2*32, cols wc2*32
    const int l15 = lane & 15;
    const int lkswz = ((lane >> 4) ^ ((l15 >> 1) & 3)) * 8;
    const u16* Abase = A + (size_t)tM * 128 * lda;
    const int stid = tid & 511;
    const int srow = stid >> 2;                       // 0..127
    const int sgc = (((stid & 3) ^ ((stid >> 3) & 3)) * 8);
    const bool isA = tid < 512;

    f32x4 acc[2][2] = {};

    auto SG = [&](int lt, int kh) {
        const int pt = lt + (lt >= 11);               // skip zero tile 11 (and 23 implicitly)
        const int base = ((lt & 1) * 2 + kh) * 4096;  // u16; parity by logical t
        if (isA)
            gload16(Abase + (size_t)srow * lda + pt * 64 + kh * 32 + sgc,
                    &LDS[base + stid * 8]);
        else
            gload16(Bt + (size_t)srow * 1536 + pt * 64 + kh * 32 + sgc,
                    &LDS[16384 + base + stid * 8]);
    };

    SG(0, 0); SG(0, 1); SG(1, 0);
    WVM(1);                                           // tile0 landed; SG(1,0) in flight
    BAR;

    const unsigned aAl = (unsigned)(size_t)&LDS[(wr2 * 32 + l15) * 32 + lkswz];
    const unsigned aBl = (unsigned)(size_t)&LDS[16384 + (wc2 * 32 + l15) * 32 + lkswz];

    #define G3MM(B0, B1, A0, A1) do { \
        __builtin_amdgcn_s_setprio(1); \
        acc[0][0] = __builtin_amdgcn_mfma_f32_16x16x32_bf16(A0, B0, acc[0][0], 0, 0, 0); \
        acc[0][1] = __builtin_amdgcn_mfma_f32_16x16x32_bf16(A0, B1, acc[0][1], 0, 0, 0); \
        acc[1][0] = __builtin_amdgcn_mfma_f32_16x16x32_bf16(A1, B0, acc[1][0], 0, 0, 0); \
        acc[1][1] = __builtin_amdgcn_mfma_f32_16x16x32_bf16(A1, B1, acc[1][1], 0, 0, 0); \
        __builtin_amdgcn_s_setprio(0); } while (0)

    for (int t = 0; t < 22; ++t) {
        const unsigned bo = (unsigned)(t & 1) * 16384u;   // byte offset (2 kh x 8KB)
        short8 a0, a1, b0, b1;
        // kh0 (staged during t-2 / prologue)
        if (t + 1 < 22) SG(t + 1, 1);
        {
            unsigned aA = aAl + bo, aB = aBl + bo;
            DSR(b0, aB, 0); DSR(b1, aB, 1024);
            DSR(a0, aA, 0); DSR(a1, aA, 1024);
        }
        LGKMN(0);
        G3MM(b0, b1, a0, a1);
        BAR;                                          // all waves done with kh0
        if (t + 2 < 22) SG(t + 2, 0);                 // overwrites this tile's kh0 region
        // kh1 (staged during t-1; landed via previous tile's vmcnt(1))
        {
            unsigned aA = aAl + bo + 8192u, aB = aBl + bo + 8192u;
            DSR(b0, aB, 0); DSR(b1, aB, 1024);
            DSR(a0, aA, 0); DSR(a1, aA, 1024);
        }
        LGKMN(0);
        G3MM(b0, b1, a0, a1);
        if (t + 2 < 22) { WVM(1); } else if (t + 1 < 22) { WVM(0); }
        BAR;
    }
    #undef G3MM

    // fused epilogue: acc -> out directly
    const int rb = tM * 128 + wr2 * 32 + ((lane >> 4) << 2);
    const int o = wc2 * 32 + l15;
    #pragma unroll
    for (int m = 0; m < 2; ++m) {
        #pragma unroll
        for (int n = 0; n < 2; ++n) {
            int oc = o + n * 16;
            #pragma unroll
            for (int j = 0; j < 4; ++j) {
                int r = rb + m * 16 + j;
                int b = r >> 10, nn = r & 1023;
                if (nn < 1000) {
                    float v = acc[m][n][j];
                    float* orow = out + ((size_t)b * 1000 + nn) * 77;
                    if (oc < 2) {
                        orow[oc] = v + cls_b[oc];
                    } else if (oc < 75) {
                        orow[oc + 2] = v + reg_b[oc - 2] + anchors[nn * 77 + oc + 2];
                        if (oc == 2) orow[2] = anchors[nn * 77 + 2];
                        if (oc == 3) orow[3] = anchors[nn * 77 + 3];
                    }
                }
            }
        }
    }
}

// ---------- softmax + diagonal-shift: wave-per-row, no barriers, no LDS ----------
__global__ __launch_bounds__(256) void k_softmax(u16* __restrict__ att) {
    const int tid = threadIdx.x;
    const int lane = tid & 63;
    const int w = blockIdx.x * 4 + (tid >> 6);       // 0..7999
    const int co0 = lane * 8, co1 = 512 + lane * 8;

    short8 c0, c1;
    {
        int b = w / 1000, n = w - b * 1000;
        const u16* rp = att + ((size_t)(b * 1024 + n)) * 1024;
        c0 = *(const short8*)&rp[co0];
        c1 = *(const short8*)&rp[co1];
    }
    for (int k = 0; k < 4; ++k) {
        const int idx = w + k * 8000;
        const int b = idx / 1000, n = idx - b * 1000;
        u16* rp = att + ((size_t)(b * 1024 + n)) * 1024;
        short8 d0 = c0, d1 = c1;
        if (k < 3) {
            int i2 = w + (k + 1) * 8000;
            int b2 = i2 / 1000, n2 = i2 - b2 * 1000;
            const u16* rp2 = att + ((size_t)(b2 * 1024 + n2)) * 1024;
            c0 = *(const short8*)&rp2[co0];
            c1 = *(const short8*)&rp2[co1];
        }
        float f0[8], f1[8];
        float m = -1e30f;
        #pragma unroll
        for (int j = 0; j < 8; ++j) {
            f0[j] = bf2f((u16)d0[j]);
            m = fmaxf(m, f0[j]);
        }
        #pragma unroll
        for (int j = 0; j < 8; ++j) {
            f1[j] = (co1 + j < 999) ? bf2f((u16)d1[j]) : -1e30f;
            m = fmaxf(m, f1[j]);
        }
        #pragma unroll
        for (int o = 32; o > 0; o >>= 1) m = fmaxf(m, __shfl_xor(m, o));
        float e0[8], e1[8];
        float s = 0.f;
        #pragma unroll
        for (int j = 0; j < 8; ++j) { e0[j] = __expf(f0[j] - m); s += e0[j]; }
        #pragma unroll
        for (int j = 0; j < 8; ++j) {
            e1[j] = (co1 + j < 999) ? __expf(f1[j] - m) : 0.f;
            s += e1[j];
        }
        #pragma unroll
        for (int o = 32; o > 0; o >>= 1) s += __shfl_xor(s, o);
        const float inv = 1.f / s;
        float p0 = __shfl_up(e0[7], 1);
        float p1 = __shfl_up(e1[7], 1);
        float x63 = __shfl(e0[7], 63);
        if (lane == 0) p1 = x63;
        short8 o0, o1;
        #pragma unroll
        for (int j = 0; j < 8; ++j) {
            int c = co0 + j;
            float pm = (j == 0) ? p0 : e0[j - 1];
            float val = (c < n) ? e0[j] : ((c > n) ? pm : 0.f);
            o0[j] = (short)f2bf(val * inv);
        }
        #pragma unroll
        for (int j = 0; j < 8; ++j) {
            int c = co1 + j;
            float pm = (j == 0) ? p1 : e1[j - 1];
            float val = 0.f;
            if (c < 1000) val = (c < n) ? e1[j] : ((c > n) ? pm : 0.f);
            o1[j] = (short)f2bf(val * inv);
        }
        *(short8*)&rp[co0] = o0;
        *(short8*)&rp[co1] = o1;
    }
}

extern "C" void kernel_launch(void* const* d_in, const int* in_sizes, int n_in,
                              void* d_out, int out_size, void* d_ws, size_t ws_size,
                              hipStream_t stream) {
    const float* x       = (const float*)d_in[0];
    const float* anchors = (const float*)d_in[1];
    const float* conv1_w = (const float*)d_in[2];
    const float* conv1_b = (const float*)d_in[3];
    const float* attn_w  = (const float*)d_in[4];
    const float* attn_b  = (const float*)d_in[5];
    const float* cls_w   = (const float*)d_in[6];
    const float* cls_b   = (const float*)d_in[7];
    const float* reg_w   = (const float*)d_in[8];
    const float* reg_b   = (const float*)d_in[9];
    const int*   cut_xs  = (const int*)d_in[12];
    const void*  invalid = d_in[13];
    float* out = (float*)d_out;

    char* ws = (char*)d_ws;
    u16*   wcat    = (u16*)  (ws + 0);           // 128x1536
    u16*   attn_wb = (u16*)  (ws + 393216);
    u16*   af      = (u16*)  (ws + 1835008);     // [32][1024][1536]
    u16*   bafT    = (u16*)  (ws + 102498304);
    u16*   att     = (u16*)  (ws + 152829952);
    float* feat    = (float*)(ws + 152829952);   // inside att, dead before G1
    int*   xn      = (int*)  (ws + 154632192);   // inside att
    float* attn_bp = (float*)(ws + 219938816);   // 1024 f32

    k_prep<<<2327, 512, 0, stream>>>(attn_w, cls_w, reg_w, cut_xs, invalid, attn_b,
                                     x, conv1_w, conv1_b,
                                     attn_wb, wcat, xn, attn_bp, feat);
    k_gat<<<dim3(192, 32), 256, 0, stream>>>(feat, xn, af, bafT);
    // G1: att = af_hi(32768x704,lda1536) x attn_wb(1024x704)^T + attn_bp
    k_g8<<<1024, 512, 0, stream>>>(af + 768, 0L, 1536, attn_wb, 0L, 704,
                                   att, 0L, 1024, 8, 1024, 1024, 22, 0, attn_bp);
    k_softmax<<<2000, 256, 0, stream>>>(att);
    // G2 (batched 32): af_lo = att(1024x1024) x bafT(768x1024)^T ; 4x6 tiles, ks=32
    k_g8<<<768, 512, 0, stream>>>(att, 1048576L, 1024, bafT, 786432L, 1024,
                                  af, 1572864L, 1536, 6, 24, 768, 32, 0, nullptr);
    // G3: out = epilogue(af(32768x1536) x wcat(128x1536)^T), zero-pad tiles skipped
    k_g3<<<256, 1024, 0, stream>>>(af, 1536, wcat, anchors, cls_b, reg_b, out, 256);
}